// Round 7
// baseline (363.855 us; speedup 1.0000x reference)
//
#include <hip/hip_runtime.h>
#include <hip/hip_bf16.h>

#define NH 8
#define BB 4
#define NN 1024
#define DD 512
#define DH 64

typedef __bf16 bf16x8 __attribute__((ext_vector_type(8)));
typedef float f32x4 __attribute__((ext_vector_type(4)));

__device__ __forceinline__ unsigned short f2bf(float f) {
    union { float f; unsigned u; } v; v.f = f;
    unsigned u = v.u;
    unsigned r = u + 0x7FFFu + ((u >> 16) & 1u);   // RNE
    return (unsigned short)(r >> 16);
}
__device__ __forceinline__ float b2f(unsigned short u) {
    union { unsigned u; float f; } cv; cv.u = ((unsigned)u) << 16; return cv.f;
}

// ---- k_prep: fused weight prep + s precompute (unchanged).
__global__ __launch_bounds__(256) void k_prep(const float* __restrict__ W,
                                              const float* __restrict__ b_proj,
                                              const float* __restrict__ w_force,
                                              unsigned short* __restrict__ Wt,
                                              float* __restrict__ bias_eff,
                                              float* __restrict__ wv_eff,
                                              float* __restrict__ s_bias) {
    __shared__ float tile[32][33];
    int bx = blockIdx.x;
    int t = threadIdx.x;
    const float rscale = 0.044194173824159216f;   // 1/sqrt(512)
    if (bx < 512) {
        int c0 = (bx & 15) * 32;   // K dim (0..511)
        int n0 = (bx >> 4) * 32;   // N dim (0..1023)
        for (int i = 0; i < 4; ++i) {
            int idx = t + i * 256;
            int r = idx >> 5, cn = idx & 31;
            tile[r][cn] = W[(c0 + r) * (3 * DD) + n0 + cn];
        }
        __syncthreads();
        for (int i = 0; i < 4; ++i) {
            int idx = t + i * 256;
            int nn = idx >> 5, cc = idx & 31;
            float v = tile[cc][nn];
            int n = n0 + nn;
            if (n < DD) v *= rscale;
            Wt[n * DD + c0 + cc] = f2bf(v);
        }
        if ((bx & 15) == 0 && t < 32) {
            int n = n0 + t;
            bias_eff[n] = b_proj[n] * (n < DD ? rscale : 1.0f);
        }
        return;
    }
    int wave = t >> 6, lane = t & 63;
    if (bx == 640) {
        if (wave == 0) {
            for (int hh = 0; hh < NH; ++hh) {
                float p = b_proj[2 * DD + hh * DH + lane] * w_force[hh * DH + lane];
                for (int off = 32; off; off >>= 1) p += __shfl_xor(p, off);
                if (lane == 0) s_bias[hh] = p;
            }
        }
        return;
    }
    int c = (bx - 512) * 4 + wave;   // 0..511
    const float* wr = W + (size_t)c * (3 * DD) + 2 * DD;
    #pragma unroll
    for (int hh = 0; hh < NH; ++hh) {
        float p = wr[hh * DH + lane] * w_force[hh * DH + lane];
        for (int off = 32; off; off >>= 1) p += __shfl_xor(p, off);
        if (lane == 0) wv_eff[c * 8 + hh] = p;
    }
}

// ---- k_s: thread per (row,h). Also writes embb (bf16 emb) for k_gemm:
// 8 threads/row each convert their 64-col slice (covers 512 cols exactly once).
__global__ __launch_bounds__(128) void k_s(const float* __restrict__ emb,
                                           const float* __restrict__ wv_eff,
                                           const float* __restrict__ s_bias,
                                           float* __restrict__ s_ws,
                                           unsigned short* __restrict__ embb) {
    int t = blockIdx.x * 128 + threadIdx.x;   // 0..32767
    int row = t >> 3;                          // b*1024 + j
    int h = t & 7;
    const float* er = emb + (size_t)row * DD;
    const float* wp = wv_eff + h;
    float acc = 0.f;
    #pragma unroll 8
    for (int c4 = 0; c4 < DD / 4; ++c4) {
        float4 e = *(const float4*)(er + c4 * 4);
        acc += e.x * wp[(c4 * 4 + 0) * 8];
        acc += e.y * wp[(c4 * 4 + 1) * 8];
        acc += e.z * wp[(c4 * 4 + 2) * 8];
        acc += e.w * wp[(c4 * 4 + 3) * 8];
    }
    int b = row >> 10, j = row & 1023;
    s_ws[(b * 8 + h) * NN + j] = acc + s_bias[h];
    // bf16 conversion of columns [h*64, h*64+64) (rows just read -> L1/L2 hot)
    unsigned short* eb = embb + (size_t)row * DD + h * 64;
    #pragma unroll
    for (int k = 0; k < 16; ++k) {
        float4 e = *(const float4*)(er + h * 64 + k * 4);
        ushort4 pk;
        pk.x = f2bf(e.x); pk.y = f2bf(e.y); pk.z = f2bf(e.z); pk.w = f2bf(e.w);
        *(ushort4*)(eb + k * 4) = pk;
    }
}

// ---- k_gemm: 128x128 tile, 4 waves, 4x4 accs/wave. NOW pure-bf16 staging
// (reads embb instead of fp32 emb): 4 uint4 loads + 4 LDS stores per thread per
// K-step, zero f2bf converts. Evidence: old staging (16 f32 loads + 32 f2bf)
// is the m33 VALU-bound signature; numerics identical (embb = f2bf(emb)).
__global__ __launch_bounds__(256) void k_gemm(const unsigned short* __restrict__ embb,
                                              const unsigned short* __restrict__ Wt,
                                              const float* __restrict__ bias_eff,
                                              unsigned short* __restrict__ qb,
                                              unsigned short* __restrict__ kb) {
    __shared__ __align__(16) unsigned short a_s[128 * 32];
    __shared__ __align__(16) unsigned short b_s[128 * 32];
    int m0 = blockIdx.x * 128, n0 = blockIdx.y * 128;
    int t = threadIdx.x;
    int wave = t >> 6, lane = t & 63;
    int wr = (wave >> 1) * 64, wc = (wave & 1) * 64;
    int qd = lane >> 4, c = lane & 15;
    int sr = t >> 2, sg = (t & 3) * 8;
    f32x4 acc[4][4] = {};
    for (int k0 = 0; k0 < DD; k0 += 32) {
        uint4 av0 = *(const uint4*)(embb + (size_t)(m0 + sr) * DD + k0 + sg);
        uint4 av1 = *(const uint4*)(embb + (size_t)(m0 + 64 + sr) * DD + k0 + sg);
        uint4 bv0 = *(const uint4*)(Wt + (size_t)(n0 + sr) * DD + k0 + sg);
        uint4 bv1 = *(const uint4*)(Wt + (size_t)(n0 + 64 + sr) * DD + k0 + sg);
        __syncthreads();
        *(uint4*)(&a_s[sr * 32 + sg]) = av0;
        *(uint4*)(&a_s[(64 + sr) * 32 + sg]) = av1;
        *(uint4*)(&b_s[sr * 32 + sg]) = bv0;
        *(uint4*)(&b_s[(64 + sr) * 32 + sg]) = bv1;
        __syncthreads();
        bf16x8 af[4], bfr[4];
        #pragma unroll
        for (int mi = 0; mi < 4; ++mi)
            af[mi] = *(const bf16x8*)(&a_s[(wr + mi * 16 + c) * 32 + qd * 8]);
        #pragma unroll
        for (int ni = 0; ni < 4; ++ni)
            bfr[ni] = *(const bf16x8*)(&b_s[(wc + ni * 16 + c) * 32 + qd * 8]);
        #pragma unroll
        for (int mi = 0; mi < 4; ++mi)
            #pragma unroll
            for (int ni = 0; ni < 4; ++ni)
                acc[mi][ni] = __builtin_amdgcn_mfma_f32_16x16x32_bf16(af[mi], bfr[ni], acc[mi][ni], 0, 0, 0);
    }
    bool isQ = (n0 < DD);
    unsigned short* dst = isQ ? qb : kb;
    int nb = isQ ? n0 : n0 - DD;
    #pragma unroll
    for (int mi = 0; mi < 4; ++mi)
        #pragma unroll
        for (int ni = 0; ni < 4; ++ni) {
            int col = nb + wc + ni * 16 + c;
            float be = bias_eff[isQ ? col : col + DD];
            #pragma unroll
            for (int r = 0; r < 4; ++r) {
                int row = m0 + wr + mi * 16 + qd * 4 + r;
                dst[(size_t)row * DD + col] = f2bf(acc[mi][ni][r] + be);
            }
        }
}

// ---- k_qk: QK^T -> global sc (bf16), ALL 4 batches in one launch (512 blocks).
// block: b=bx>>7, h=(bx>>4)&7, itile=bx&15 -> i0=itile*64. Wave w owns j-slice
// [w*256,(w+1)*256). Verified orientation: lane holds sc[j=j0+qd*4+r][i=i0+s*16+c].
__global__ __launch_bounds__(256) void k_qk(const unsigned short* __restrict__ qb,
                                            const unsigned short* __restrict__ kb,
                                            unsigned short* __restrict__ sc) {
    int bx = blockIdx.x;
    int b = bx >> 7;
    int h = (bx >> 4) & 7;
    int itile = bx & 15;
    int i0 = itile * 64;
    int t = threadIdx.x;
    int w = t >> 6, lane = t & 63, qd = lane >> 4, c = lane & 15;

    bf16x8 aq0[4], aq1[4];
    #pragma unroll
    for (int s = 0; s < 4; ++s) {
        const unsigned short* qbase =
            qb + ((size_t)(b * NN + i0 + s * 16 + c) * DD + h * DH + qd * 8);
        aq0[s] = *(const bf16x8*)(qbase);
        aq1[s] = *(const bf16x8*)(qbase + 32);
    }
    unsigned short* scb = sc + ((size_t)(b * NH + h)) * NN * NN;
    int j0w = w * 256;
    #pragma unroll
    for (int jt = 0; jt < 16; ++jt) {
        int j0 = j0w + jt * 16;
        const unsigned short* kba =
            kb + ((size_t)(b * NN + j0 + c) * DD + h * DH + qd * 8);
        bf16x8 kf0 = *(const bf16x8*)(kba);
        bf16x8 kf1 = *(const bf16x8*)(kba + 32);
        #pragma unroll
        for (int s = 0; s < 4; ++s) {
            f32x4 a = {0.f, 0.f, 0.f, 0.f};
            a = __builtin_amdgcn_mfma_f32_16x16x32_bf16(kf0, aq0[s], a, 0, 0, 0);
            a = __builtin_amdgcn_mfma_f32_16x16x32_bf16(kf1, aq1[s], a, 0, 0, 0);
            ushort4 pk;
            pk.x = f2bf(a[0]); pk.y = f2bf(a[1]); pk.z = f2bf(a[2]); pk.w = f2bf(a[3]);
            *(ushort4*)(scb + (size_t)(i0 + s * 16 + c) * NN + j0 + qd * 4) = pk;
        }
    }
}

// ---- k_soft: zero-LDS streaming softmax+weighted-sum, ALL 4 batches (4096 blocks).
// block=(b,i-row), wave w = head w: head-sharing without spills, dirs row fetched
// once per block (8 waves hit L1/L2). Occupancy VGPR-capped, no LDS.
__global__ __launch_bounds__(512, 4) void k_soft(const unsigned short* __restrict__ sc,
                                                 const float* __restrict__ s_ws,
                                                 const float* __restrict__ d_mask,
                                                 const float* __restrict__ dirs,
                                                 float* __restrict__ part) {
    int bx = blockIdx.x;
    int b = bx >> 10;
    int i = bx & 1023;
    int t = threadIdx.x;
    int h = t >> 6, lane = t & 63;
    int bh = b * NH + h;

    const float* sm = s_ws + (size_t)bh * NN;
    float4 sv[4];
    #pragma unroll
    for (int seg = 0; seg < 4; ++seg)
        sv[seg] = *(const float4*)(sm + seg * 256 + lane * 4);

    const float* mrow = d_mask + ((size_t)bh * NN + i) * NN + lane * 4;
    const float* drow = dirs + ((size_t)(b * NN + i) * NN + (size_t)(lane * 4)) * 3;
    const unsigned short* scrow = sc + ((size_t)bh * NN + i) * NN + lane * 4;

    float l = 0.f, a0 = 0.f, a1 = 0.f, a2 = 0.f;
    #pragma unroll
    for (int seg = 0; seg < 4; ++seg) {
        float4 mk = *(const float4*)(mrow + seg * 256);
        float4 d0 = *(const float4*)(drow + seg * 768);
        float4 d1 = *(const float4*)(drow + seg * 768 + 4);
        float4 d2 = *(const float4*)(drow + seg * 768 + 8);
        ushort4 scv = *(const ushort4*)(scrow + seg * 256);
        float p0 = __expf(b2f(scv.x) + mk.x);
        float p1 = __expf(b2f(scv.y) + mk.y);
        float p2 = __expf(b2f(scv.z) + mk.z);
        float p3 = __expf(b2f(scv.w) + mk.w);
        l += p0 + p1 + p2 + p3;
        float t0 = p0 * sv[seg].x, t1 = p1 * sv[seg].y;
        float t2 = p2 * sv[seg].z, t3 = p3 * sv[seg].w;
        // dirs: j+0 -> d0.xyz ; j+1 -> d0.w d1.xy ; j+2 -> d1.zw d2.x ; j+3 -> d2.yzw
        a0 += t0 * d0.x + t1 * d0.w + t2 * d1.z + t3 * d2.y;
        a1 += t0 * d0.y + t1 * d1.x + t2 * d1.w + t3 * d2.z;
        a2 += t0 * d0.z + t1 * d1.y + t2 * d2.x + t3 * d2.w;
    }

    #pragma unroll
    for (int off = 1; off < 64; off <<= 1) {
        l  += __shfl_xor(l, off);
        a0 += __shfl_xor(a0, off);
        a1 += __shfl_xor(a1, off);
        a2 += __shfl_xor(a2, off);
    }
    if (lane == 0) {
        f32x4 o; o[0] = l; o[1] = a0; o[2] = a1; o[3] = a2;
        *(f32x4*)(part + ((size_t)bh * NN + i) * 4) = o;
    }
}

// ---- k_fin: out[b,i,a] = b_force + sum_h acc[b,h,i,a] / l[b,h,i] (unchanged)
__global__ __launch_bounds__(256) void k_fin(const float4* __restrict__ part,
                                             const float* __restrict__ b_force,
                                             float* __restrict__ out) {
    int t = blockIdx.x * 256 + threadIdx.x;   // 0..4095
    int b = t >> 10, i = t & 1023;
    float o0, o1, o2;
    o0 = o1 = o2 = b_force[0];
    #pragma unroll
    for (int h = 0; h < NH; ++h) {
        float4 p = part[(((size_t)(b * NH + h)) << 10) + i];
        float inv = 1.0f / p.x;
        o0 += p.y * inv; o1 += p.z * inv; o2 += p.w * inv;
    }
    out[t * 3 + 0] = o0;
    out[t * 3 + 1] = o1;
    out[t * 3 + 2] = o2;
}

extern "C" void kernel_launch(void* const* d_in, const int* in_sizes, int n_in,
                              void* d_out, int out_size, void* d_ws, size_t ws_size,
                              hipStream_t stream) {
    (void)in_sizes; (void)n_in; (void)out_size; (void)ws_size;
    const float* emb     = (const float*)d_in[0];
    const float* dirs    = (const float*)d_in[1];
    const float* d_mask  = (const float*)d_in[2];
    const float* W       = (const float*)d_in[3];
    const float* b_proj  = (const float*)d_in[4];
    const float* w_force = (const float*)d_in[5];
    const float* b_force = (const float*)d_in[6];
    float* out = (float*)d_out;

    char* ws = (char*)d_ws;
    float* wv_eff   = (float*)ws;                       // 4096 f
    float* s_bias   = wv_eff + 4096;                    // 8 f
    float* bias_eff = s_bias + 8;                       // 1024 f
    float* s_ws     = bias_eff + 1024;                  // 32768 f
    unsigned short* Wt = (unsigned short*)(s_ws + 32768);    // 512K elems (1 MB)
    unsigned short* qb = Wt + 1024 * 512;               // 2M elems (4 MB)
    unsigned short* kb = qb + 4096 * 512;               // 2M elems (4 MB)
    float* part = (float*)(kb + 4096 * 512);            // 32*1024 float4 = 512 KB
    unsigned short* scg  = (unsigned short*)(part + 32 * 1024 * 4);  // 4*8*1024*1024 bf16 = 64 MB
    unsigned short* embb = scg + (size_t)BB * NH * NN * NN;          // 4096*512 bf16 = 4 MB

    hipLaunchKernelGGL(k_prep, dim3(641),      dim3(256), 0, stream,
                       W, b_proj, w_force, Wt, bias_eff, wv_eff, s_bias);
    hipLaunchKernelGGL(k_s,    dim3(256),      dim3(128), 0, stream,
                       emb, wv_eff, s_bias, s_ws, embb);
    hipLaunchKernelGGL(k_gemm, dim3(32, 8),    dim3(256), 0, stream,
                       embb, Wt, bias_eff, qb, kb);
    hipLaunchKernelGGL(k_qk,   dim3(512),      dim3(256), 0, stream, qb, kb, scg);
    hipLaunchKernelGGL(k_soft, dim3(4096),     dim3(512), 0, stream,
                       scg, s_ws, d_mask, dirs, part);
    hipLaunchKernelGGL(k_fin,  dim3(16),       dim3(256), 0, stream, (const float4*)part, b_force, out);
}